// Round 6
// baseline (10722.574 us; speedup 1.0000x reference)
//
#include <hip/hip_runtime.h>

// EvolvedNet: 32-node graph relaxation, 128 edges applied sequentially per
// sweep, 32 sweeps, batched over 524288 independent elements.
//
// R1: 743us @ BLOCK=256/EPT=1, VALU 91%. wall/edge ~180cy: false RAW
//     serialization (compiler can't disprove vals[src_{e+1}] vs vals[dst_e]
//     alias -> every read waits behind prior write; ~120cy LDS latency/edge).
// R2: per-edge wave-uniform branch REGRESSED (1230us). Branch-free only.
// R3/R5: EPT=2 packing cut issue (30cy/elem) but LDS/wave doubled -> waves
//     halved -> latency-bound (48-57% busy). time ∝ wall/waves; wash.
// R4: atomicAdd through char* cast -> flat atomics, 10.7ms. Typed LDS only.
// R6: break the false serialization: software-pipeline src reads K=2 edges
//     ahead (read for e+2 issues BEFORE ds_add(e) in program order - legal
//     hoist of load above may-alias store), and repair the missed updates at
//     consume time with prep-computed 0/1 multipliers:
//       v = fma(g2[e], t[e-2], p0); v = fma(g1[e], t[e-1], v)
//     (older first -> bit-exact vs sequential reference; masks cyclic mod 128
//     so the pipeline runs seamlessly across sweeps; t1=t2=0 covers sweep 0).
//     Accumulate with ds_add_f32 (typed __shared__, workgroup scope) - no
//     read-modify-write tail. Edge constants as packed global records ->
//     vmcnt (separate counter), so const loads can't drain the DS pipeline.

#define N_NODES   32
#define N_INPUTS  8
#define N_OUTPUTS 4
#define N_EDGES   128
#define BATCH     524288
#define BLOCK     256

// 2 * log2(e)
#define TWO_LOG2E 2.88539008177792681472f

struct __align__(16) EdgeRec {
    int   soff;   // src * BLOCK (element offset of node row)
    int   doff;   // dst * BLOCK
    float wk;     // w * 2log2e
    float g1;     // 1.0 if src[e] == dst[e-1 mod 128] else 0.0
};

// Pre-kernel: per-edge uniform precompute into d_ws (graph-safe, runs every
// call, deterministic).
__global__ void EvolvedNet_prep(const float* __restrict__ w,
                                const int*   __restrict__ src,
                                const int*   __restrict__ dst,
                                EdgeRec* __restrict__ rec,
                                float*   __restrict__ g2) {
    const int e = threadIdx.x;
    if (e < N_EDGES) {
        EdgeRec r;
        r.soff = src[e] * BLOCK;
        r.doff = dst[e] * BLOCK;
        r.wk   = w[e] * TWO_LOG2E;   // same f32 op as R1 -> bit-identical
        r.g1   = (src[e] == dst[(e + N_EDGES - 1) & (N_EDGES - 1)]) ? 1.0f : 0.0f;
        rec[e] = r;
        g2[e]  = (src[e] == dst[(e + N_EDGES - 2) & (N_EDGES - 1)]) ? 1.0f : 0.0f;
    }
}

__global__ __launch_bounds__(BLOCK)
void EvolvedNet_80032420593868_kernel(const float* __restrict__ x,
                                      const EdgeRec* __restrict__ rec,
                                      const float*   __restrict__ g2,
                                      float*         __restrict__ out) {
    // vals[node*BLOCK + tid]: wave-uniform node index -> lanes on consecutive
    // banks (2-way aliasing over wave64 = free). Typed indexing ONLY (R4).
    __shared__ float vals[N_NODES * BLOCK];

    const int tid = threadIdx.x;
    const int b   = blockIdx.x * BLOCK + tid;

#pragma unroll
    for (int n = 0; n < N_INPUTS; ++n)
        vals[n * BLOCK + tid] = x[n * BATCH + b];
#pragma unroll
    for (int n = N_INPUTS; n < N_NODES; ++n)
        vals[n * BLOCK + tid] = 0.0f;

    // No __syncthreads anywhere: each thread touches only its own column;
    // per-thread DS ops execute in order (sequential edge semantics kept).

    // Pipeline prologue: reads for edges 0 and 1 (no adds issued yet, and
    // t1=t2=0 neutralizes their cyclic fixup masks for sweep 0).
    float p0 = vals[rec[0].soff + tid];   // consumed at iteration 0
    float p1 = vals[rec[1].soff + tid];   // consumed at iteration 1
    float t1 = 0.0f, t2 = 0.0f;           // t of edges e-1, e-2

    for (int sweep = 0; sweep < N_NODES; ++sweep) {
#pragma unroll 8
        for (int e = 0; e < N_EDGES; ++e) {
            // (1) pipelined read for edge e+2's src (wraps to next sweep's
            // first edges at e=126,127 - masks are cyclic, so it just works;
            // the final sweep's 2 wrap reads are dead but harmless).
            const int   er = (e + 2) & (N_EDGES - 1);
            const float vr = vals[rec[er].soff + tid];

            // (2) consume p0 = src value of edge e, read 2 iterations ago;
            // repair the two possibly-missed updates, OLDEST FIRST so the
            // add sequence matches the reference bit-for-bit.
            const EdgeRec r = rec[e];
            float v = __builtin_fmaf(g2[e], t2, p0);   // + t[e-2] if dst match
            v       = __builtin_fmaf(r.g1, t1, v);     // + t[e-1] if dst match

            const float a  = v * r.wk;
            const float u  = __builtin_amdgcn_exp2f(a);
            const float rc = __builtin_amdgcn_rcpf(1.0f + u);
            const float t  = __builtin_fmaf(-2.0f, rc, 1.0f);  // 1 - 2/(1+u)

            // (3) accumulate: ds_add_f32 (no return). DS pipe is in-order,
            // so edge-order of adds is preserved; IEEE RTN same as v_add.
            __hip_atomic_fetch_add(&vals[r.doff + tid], t,
                                   __ATOMIC_RELAXED, __HIP_MEMORY_SCOPE_WORKGROUP);

            // rotate pipeline registers (SSA, no arrays - rule #20 safe)
            p0 = p1; p1 = vr;
            t2 = t1; t1 = t;
        }
    }

    // outputs: tanh(vals[28..31]); ds reads ordered after all adds.
#pragma unroll
    for (int o = 0; o < N_OUTPUTS; ++o) {
        const float v = vals[(N_NODES - N_OUTPUTS + o) * BLOCK + tid];
        const float u = __builtin_amdgcn_exp2f(v * TWO_LOG2E);
        out[o * BATCH + b] = __builtin_fmaf(-2.0f, __builtin_amdgcn_rcpf(1.0f + u), 1.0f);
    }
}

extern "C" void kernel_launch(void* const* d_in, const int* in_sizes, int n_in,
                              void* d_out, int out_size, void* d_ws, size_t ws_size,
                              hipStream_t stream) {
    const float* x   = (const float*)d_in[0];
    const float* w   = (const float*)d_in[1];
    const int*   src = (const int*)d_in[2];
    const int*   dst = (const int*)d_in[3];
    float*       out = (float*)d_out;

    // d_ws layout: rec[128] (2048B, 16B-aligned) | g2[128] (512B)
    EdgeRec* rec = (EdgeRec*)d_ws;
    float*   g2  = (float*)((char*)d_ws + N_EDGES * sizeof(EdgeRec));

    EvolvedNet_prep<<<1, 128, 0, stream>>>(w, src, dst, rec, g2);

    const int grid = BATCH / BLOCK;  // 2048 blocks, exact
    EvolvedNet_80032420593868_kernel<<<grid, BLOCK, 0, stream>>>(x, rec, g2, out);
}

// Round 7
// 969.701 us; speedup vs baseline: 11.0576x; 11.0576x over previous
//
#include <hip/hip_runtime.h>

// EvolvedNet: 32-node graph relaxation, 128 edges applied sequentially per
// sweep, 32 sweeps, batched over 524288 independent elements.
//
// R1: 743us @BLOCK=256/EPT=1, VALU 91% -> ISSUE-bound, 49.5cy/elem-edge.
// R2: per-edge branch REGRESSED (1230us). Branch-free inner loop only.
// R3/R5: EPT=2 f32x2 halves issue (30cy/elem) but 32KB blocks -> 3 blocks/CU
//     (empirical) -> 1.5 waves/SIMD -> latency-bound 48%, 850us.
// R4/R6: LDS float atomics (typed or not) -> ~15x collapse (10.7ms, VALU 5%).
//     NEVER use LDS atomics here; explicit read-modify-write only.
//     (R6 did verify the fixup-forwarding algebra: absmax bit-identical.)
// R7: EPT=2 pk math + K=2 software-pipelined LDS reads for BOTH src and dst,
//     explicit RMW write. Reads for edge e+2 issue before the write of edge e
//     (program order, may-alias -> compiler & in-order DS pipe preserve it),
//     so they miss writes of e,e+1; prep-computed {0,1} multipliers repair at
//     consume time, oldest first -> BIT-EXACT vs sequential reference:
//       v  = (ps0 + g2*t2) + g1*t1      (g*t exact since g in {0,1})
//       dv = (pd0 + h2*t2) + h1*t1
//     Masks cyclic mod 128 -> pipeline flows across sweep boundaries;
//     prologue t1=t2=0 covers sweep 0.

#define N_NODES   32
#define N_INPUTS  8
#define N_OUTPUTS 4
#define N_EDGES   128
#define BATCH     524288
#define BLOCK     128                // threads per block (2 waves)
#define EPT       2
#define TILE      (BLOCK * EPT)     // 256 elements per block

// 2 * log2(e)
#define TWO_LOG2E 2.88539008177792681472f

typedef float f32x2 __attribute__((ext_vector_type(2)));

struct __align__(16) ERec  { int soff, doff; float wk, pad; };
struct __align__(16) EFix  { float g1, g2, h1, h2; };

// Pre-kernel: per-edge uniform precompute into d_ws (graph-safe, runs every
// call, deterministic).
__global__ void EvolvedNet_prep(const float* __restrict__ w,
                                const int*   __restrict__ src,
                                const int*   __restrict__ dst,
                                ERec* __restrict__ rec,
                                EFix* __restrict__ fix) {
    const int e = threadIdx.x;
    if (e < N_EDGES) {
        ERec r;
        r.soff = src[e] * BLOCK;     // row offset in f32x2 elements
        r.doff = dst[e] * BLOCK;
        r.wk   = w[e] * TWO_LOG2E;   // same f32 op as R1 -> bit-identical
        r.pad  = 0.0f;
        rec[e] = r;
        const int em1 = (e + N_EDGES - 1) & (N_EDGES - 1);
        const int em2 = (e + N_EDGES - 2) & (N_EDGES - 1);
        EFix f;
        f.g1 = (src[e] == dst[em1]) ? 1.0f : 0.0f;
        f.g2 = (src[e] == dst[em2]) ? 1.0f : 0.0f;
        f.h1 = (dst[e] == dst[em1]) ? 1.0f : 0.0f;
        f.h2 = (dst[e] == dst[em2]) ? 1.0f : 0.0f;
        fix[e] = f;
    }
}

__global__ __launch_bounds__(BLOCK)
void EvolvedNet_80032420593868_kernel(const float* __restrict__ x,
                                      const ERec* __restrict__ rec,
                                      const EFix* __restrict__ fix,
                                      float*      __restrict__ out) {
    // vals[node*BLOCK + tid]: per-thread f32x2 column. Wave-uniform node
    // index -> lanes hit consecutive 8B slots: conflict-free. Typed LDS
    // indexing only (R4), no atomics (R6).
    __shared__ f32x2 vals[N_NODES * BLOCK];

    const int tid = threadIdx.x;
    const int b0  = blockIdx.x * TILE + tid * 2;

#pragma unroll
    for (int n = 0; n < N_INPUTS; ++n)
        vals[n * BLOCK + tid] = *(const f32x2*)&x[n * BATCH + b0];
#pragma unroll
    for (int n = N_INPUTS; n < N_NODES; ++n)
        vals[n * BLOCK + tid] = (f32x2)(0.0f, 0.0f);

    // No __syncthreads: each thread touches only its own column; per-thread
    // DS ops execute in order (sequential edge semantics preserved).

    // Pipeline prologue: reads for edges 0,1 (after init writes, before any
    // edge write -> they see the true initial state; t1=t2=0 makes the
    // cyclic fixup masks neutral for sweep 0).
    f32x2 ps0 = vals[rec[0].soff + tid];
    f32x2 ps1 = vals[rec[1].soff + tid];
    f32x2 pd0 = vals[rec[0].doff + tid];
    f32x2 pd1 = vals[rec[1].doff + tid];
    f32x2 t1 = (f32x2)(0.0f, 0.0f), t2 = (f32x2)(0.0f, 0.0f);

    for (int sweep = 0; sweep < N_NODES; ++sweep) {
#pragma unroll 8
        for (int e = 0; e < N_EDGES; ++e) {
            // (1) pipelined reads for edge e+2 (wrap to next sweep's first
            // edges; cyclic masks make it seamless; last sweep's 2 extra
            // reads are dead but harmless). Program order: BEFORE write(e).
            const int  er = (e + 2) & (N_EDGES - 1);
            const ERec rn = rec[er];
            const f32x2 vs = vals[rn.soff + tid];
            const f32x2 vd = vals[rn.doff + tid];

            // (2) consume values read 2 iterations ago; repair the two
            // possibly-missed updates, OLDEST FIRST (bit-exact: f*t is
            // exact for f in {0,1}, then plain IEEE add).
            const ERec r = rec[e];
            const EFix f = fix[e];
            f32x2 v  = ps0 + t2 * f.g2;
            v        = v   + t1 * f.g1;
            f32x2 dv = pd0 + t2 * f.h2;
            dv       = dv  + t1 * f.h1;

            const f32x2 a = v * r.wk;
            f32x2 t;
            t.x = __builtin_fmaf(-2.0f,
                    __builtin_amdgcn_rcpf(1.0f + __builtin_amdgcn_exp2f(a.x)), 1.0f);
            t.y = __builtin_fmaf(-2.0f,
                    __builtin_amdgcn_rcpf(1.0f + __builtin_amdgcn_exp2f(a.y)), 1.0f);

            // (3) explicit RMW write (NO atomics). In-order DS pipe keeps
            // edge order; dv+t is the same IEEE add as the reference.
            vals[r.doff + tid] = dv + t;

            // rotate pipeline registers (pure SSA, rule #20 safe)
            ps0 = ps1; ps1 = vs;
            pd0 = pd1; pd1 = vd;
            t2 = t1;   t1 = t;
        }
    }

    // outputs: tanh(vals[28..31]); out is [N_OUTPUTS][BATCH] flat, 8B stores.
#pragma unroll
    for (int o = 0; o < N_OUTPUTS; ++o) {
        const f32x2 v = vals[(N_NODES - N_OUTPUTS + o) * BLOCK + tid];
        f32x2 t;
        t.x = __builtin_fmaf(-2.0f,
                __builtin_amdgcn_rcpf(1.0f + __builtin_amdgcn_exp2f(v.x * TWO_LOG2E)), 1.0f);
        t.y = __builtin_fmaf(-2.0f,
                __builtin_amdgcn_rcpf(1.0f + __builtin_amdgcn_exp2f(v.y * TWO_LOG2E)), 1.0f);
        *(f32x2*)&out[o * BATCH + b0] = t;
    }
}

extern "C" void kernel_launch(void* const* d_in, const int* in_sizes, int n_in,
                              void* d_out, int out_size, void* d_ws, size_t ws_size,
                              hipStream_t stream) {
    const float* x   = (const float*)d_in[0];
    const float* w   = (const float*)d_in[1];
    const int*   src = (const int*)d_in[2];
    const int*   dst = (const int*)d_in[3];
    float*       out = (float*)d_out;

    // d_ws layout: rec[128] (2048B) | fix[128] (2048B)
    ERec* rec = (ERec*)d_ws;
    EFix* fixp = (EFix*)((char*)d_ws + N_EDGES * sizeof(ERec));

    EvolvedNet_prep<<<1, 128, 0, stream>>>(w, src, dst, rec, fixp);

    const int grid = BATCH / TILE;   // 2048 blocks, exact
    EvolvedNet_80032420593868_kernel<<<grid, BLOCK, 0, stream>>>(x, rec, fixp, out);
}

// Round 8
// 840.618 us; speedup vs baseline: 12.7556x; 1.1536x over previous
//
#include <hip/hip_runtime.h>

// EvolvedNet: 32-node graph relaxation, 128 edges applied sequentially per
// sweep, 32 sweeps, batched over 524288 independent elements.
//
// R1: 743us @EPT=1, VALU 91%, 49.5cy/elem-edge.
// R2: per-edge branch REGRESSED (1230us). Branch-free inner loop only.
// R3/R5: EPT=2 f32x2 halves issue (60cy/pair) but latency-bound 48%, 850us.
// R4/R6: LDS float atomics -> ~15x collapse. Explicit RMW only.
// R7: K=2 pipeline + fixups NULL (1085us, 55% busy). DIAGNOSIS: per-edge
//     uniform loads are s_load (SMEM); SMEM+DS share lgkmcnt but complete
//     out-of-order w.r.t. each other -> compiler must drain lgkmcnt(0) at
//     every DS consume -> prefetch nullified. (Fixup algebra verified
//     bit-exact in R6/R7.)
// R8: purge the lgkm domain: NO loads in the inner loop. Edge data preloaded
//     once into lane-distributed VGPRs (128 edges / 64 lanes = 2 regs x 5
//     fields); inner 128-edge loop FULLY UNROLLED so v_readlane uses
//     compile-time lane indices. lgkm domain = in-order DS only -> counted
//     lgkmcnt(N) waits -> K=2 src prefetch + bit-exact {0,1}-fixup works:
//       v = fma(g1, t1, fma(g2, t2, ps0))   (oldest first, g*t exact)
//     dst read moved in-iteration (in-order DS pipe sees write(e-1)), no
//     dst fixup needed.

#define N_NODES   32
#define N_INPUTS  8
#define N_OUTPUTS 4
#define N_EDGES   128
#define BATCH     524288
#define BLOCK     128                // 2 waves/block
#define EPT       2
#define TILE      (BLOCK * EPT)      // 256 elements/block

// 2 * log2(e)
#define TWO_LOG2E 2.88539008177792681472f

typedef float f32x2 __attribute__((ext_vector_type(2)));

// Pre-kernel: per-edge uniform precompute into d_ws (graph-safe, runs every
// call, deterministic). Offsets in f32x2 elements.
__global__ void EvolvedNet_prep(const float* __restrict__ w,
                                const int*   __restrict__ src,
                                const int*   __restrict__ dst,
                                int* __restrict__ soff, int* __restrict__ doff,
                                float* __restrict__ wk,
                                float* __restrict__ g1, float* __restrict__ g2) {
    const int e = threadIdx.x;
    if (e < N_EDGES) {
        soff[e] = src[e] * BLOCK;
        doff[e] = dst[e] * BLOCK;
        wk[e]   = w[e] * TWO_LOG2E;   // same f32 op as R1 -> bit-identical
        const int em1 = (e + N_EDGES - 1) & (N_EDGES - 1);
        const int em2 = (e + N_EDGES - 2) & (N_EDGES - 1);
        g1[e] = (src[e] == dst[em1]) ? 1.0f : 0.0f;
        g2[e] = (src[e] == dst[em2]) ? 1.0f : 0.0f;
    }
}

// readlane from lane-distributed 2-reg arrays; E compile-time after unroll
// -> constant lane index + constant register index (rule #20 safe).
#define RLI(arr, E) __builtin_amdgcn_readlane(arr[(E) >> 6], (E) & 63)
#define RLF(arr, E) __uint_as_float((unsigned)__builtin_amdgcn_readlane( \
                        (int)__float_as_uint(arr[(E) >> 6]), (E) & 63))

__global__ __launch_bounds__(BLOCK)
void EvolvedNet_80032420593868_kernel(const float* __restrict__ x,
                                      const int*   __restrict__ soff,
                                      const int*   __restrict__ doff,
                                      const float* __restrict__ wk,
                                      const float* __restrict__ g1,
                                      const float* __restrict__ g2,
                                      float*       __restrict__ out) {
    // vals[node*BLOCK + tid]: per-thread f32x2 column; wave-uniform node
    // index -> lanes on consecutive 8B slots, conflict-free. Typed indexing
    // only (R4), no atomics (R6).
    __shared__ f32x2 vals[N_NODES * BLOCK];

    const int tid  = threadIdx.x;
    const int lane = tid & 63;
    const int b0   = blockIdx.x * TILE + tid * 2;

    // ---- preload ALL edge data into lane-distributed VGPRs (once) ----
    int   rs[2], rd[2];
    float rw[2], r1[2], r2[2];
    rs[0] = soff[lane];  rs[1] = soff[lane + 64];
    rd[0] = doff[lane];  rd[1] = doff[lane + 64];
    rw[0] = wk[lane];    rw[1] = wk[lane + 64];
    r1[0] = g1[lane];    r1[1] = g1[lane + 64];
    r2[0] = g2[lane];    r2[1] = g2[lane + 64];

    // ---- init node state ----
#pragma unroll
    for (int n = 0; n < N_INPUTS; ++n)
        vals[n * BLOCK + tid] = *(const f32x2*)&x[n * BATCH + b0];
#pragma unroll
    for (int n = N_INPUTS; n < N_NODES; ++n)
        vals[n * BLOCK + tid] = (f32x2)(0.0f, 0.0f);

    // No __syncthreads: each thread touches only its own column; per-thread
    // DS ops execute in order (sequential edge semantics preserved).

    // Pipeline prologue: src reads for edges 0,1; t1=t2=0 neutralizes the
    // cyclic fixup masks for sweep 0.
    f32x2 ps0 = vals[RLI(rs, 0) + tid];
    f32x2 ps1 = vals[RLI(rs, 1) + tid];
    f32x2 t1 = (f32x2)(0.0f, 0.0f), t2 = (f32x2)(0.0f, 0.0f);

    for (int sweep = 0; sweep < N_NODES; ++sweep) {
        // FULL unroll: makes every readlane lane index & register index a
        // compile-time constant; zero loads in the loop -> lgkm domain is
        // pure in-order DS -> counted waits, prefetch stays outstanding.
#pragma unroll
        for (int e = 0; e < N_EDGES; ++e) {
            // (1) prefetch src of edge e+2 (cyclic wrap across sweeps).
            // Program order keeps it between write(e-1) and write(e):
            // misses exactly writes e,e+1 -> repaired by g1/g2 fixup.
            const int   son = RLI(rs, (e + 2) & (N_EDGES - 1));
            const f32x2 vs  = vals[son + tid];

            // (2) dst current value: issued early, sees write(e-1) via
            // in-order DS pipe; no fixup needed.
            const int   dof = RLI(rd, e);
            const f32x2 dv  = vals[dof + tid];

            // (3) consume src value read 2 iters ago; repair possibly-missed
            // updates OLDEST FIRST (bit-exact: g in {0,1}).
            const float g2s = RLF(r2, e);
            const float g1s = RLF(r1, e);
            const float wks = RLF(rw, e);
            f32x2 v;
            v.x = __builtin_fmaf(g2s, t2.x, ps0.x);
            v.y = __builtin_fmaf(g2s, t2.y, ps0.y);
            v.x = __builtin_fmaf(g1s, t1.x, v.x);
            v.y = __builtin_fmaf(g1s, t1.y, v.y);

            const f32x2 a = v * wks;
            f32x2 t;
            t.x = __builtin_fmaf(-2.0f,
                    __builtin_amdgcn_rcpf(1.0f + __builtin_amdgcn_exp2f(a.x)), 1.0f);
            t.y = __builtin_fmaf(-2.0f,
                    __builtin_amdgcn_rcpf(1.0f + __builtin_amdgcn_exp2f(a.y)), 1.0f);

            // (4) explicit RMW write; in-order DS pipe keeps edge order.
            vals[dof + tid] = dv + t;

            // rotate pipeline (SSA under full unroll)
            ps0 = ps1; ps1 = vs;
            t2 = t1;   t1 = t;
        }
    }

    // outputs: tanh(vals[28..31]); out is [N_OUTPUTS][BATCH] flat, 8B stores.
#pragma unroll
    for (int o = 0; o < N_OUTPUTS; ++o) {
        const f32x2 v = vals[(N_NODES - N_OUTPUTS + o) * BLOCK + tid];
        f32x2 t;
        t.x = __builtin_fmaf(-2.0f,
                __builtin_amdgcn_rcpf(1.0f + __builtin_amdgcn_exp2f(v.x * TWO_LOG2E)), 1.0f);
        t.y = __builtin_fmaf(-2.0f,
                __builtin_amdgcn_rcpf(1.0f + __builtin_amdgcn_exp2f(v.y * TWO_LOG2E)), 1.0f);
        *(f32x2*)&out[o * BATCH + b0] = t;
    }
}

extern "C" void kernel_launch(void* const* d_in, const int* in_sizes, int n_in,
                              void* d_out, int out_size, void* d_ws, size_t ws_size,
                              hipStream_t stream) {
    const float* x   = (const float*)d_in[0];
    const float* w   = (const float*)d_in[1];
    const int*   src = (const int*)d_in[2];
    const int*   dst = (const int*)d_in[3];
    float*       out = (float*)d_out;

    // d_ws layout: soff[128] | doff[128] | wk[128] | g1[128] | g2[128]
    int*   soff = (int*)d_ws;
    int*   doff = soff + N_EDGES;
    float* wkp  = (float*)(doff + N_EDGES);
    float* g1p  = wkp + N_EDGES;
    float* g2p  = g1p + N_EDGES;

    EvolvedNet_prep<<<1, 128, 0, stream>>>(w, src, dst, soff, doff, wkp, g1p, g2p);

    const int grid = BATCH / TILE;   // 2048 blocks, exact
    EvolvedNet_80032420593868_kernel<<<grid, BLOCK, 0, stream>>>(
        x, soff, doff, wkp, g1p, g2p, out);
}

// Round 9
// 698.592 us; speedup vs baseline: 15.3488x; 1.2033x over previous
//
#include <hip/hip_runtime.h>

// EvolvedNet: 32-node graph relaxation, 128 edges applied sequentially per
// sweep, 32 sweeps, batched over 524288 independent elements.
//
// R1: 743us @EPT=1/BLOCK=256, busy 91%: WALL-bound (~178cy/iter) on the
//     write(e)->read(e+1) serialization; issue 49.5cy.
// R2: per-edge branch REGRESSED. Branch-free only.
// R3/R5: EPT=2: LDS caps resident elements at ~832/CU -> waves halve ->
//     latency-bound. EPT=1 is strictly better (pk-f32 never materializes).
// R4/R6: LDS float atomics -> 15x collapse. Explicit RMW only.
// R7: SMEM in loop shares lgkmcnt with DS, completes out-of-order -> full
//     drains kill prefetching. No SMEM in the inner loop.
// R8: lgkm purge via readlane worked (busy 55->67%) but EPT=2 + fixups +
//     rotation bloated issue to 100cy/pair. Fixups are NOT needed:
// R9: EPT=1 + read-ahead of src(e+1),dst(e+1) issued AFTER write(e) in
//     program order. In-order DS pipe => read returns post-write data =>
//     exact sequential semantics, no fixups. ~64cy read latency is covered
//     by 3.28 waves/SIMD (needs ~2.5). Edge constants readlane'd from
//     lane-distributed VGPRs (full unroll; sodo packed, SALU unpack).

#define N_NODES   32
#define N_INPUTS  8
#define N_OUTPUTS 4
#define N_EDGES   128
#define BATCH     524288
#define BLOCK     256

// 2 * log2(e)
#define TWO_LOG2E 2.88539008177792681472f

// Pre-kernel: per-edge uniform precompute into d_ws (graph-safe, runs every
// call, deterministic). sodo packs src/dst LDS ELEMENT offsets (node*BLOCK,
// max 31*256=7936, fits u16).
__global__ void EvolvedNet_prep(const float* __restrict__ w,
                                const int*   __restrict__ src,
                                const int*   __restrict__ dst,
                                unsigned* __restrict__ sodo,
                                float*    __restrict__ wk) {
    const int e = threadIdx.x;
    if (e < N_EDGES) {
        sodo[e] = (unsigned)(src[e] * BLOCK) | ((unsigned)(dst[e] * BLOCK) << 16);
        wk[e]   = w[e] * TWO_LOG2E;   // same f32 op as R1 -> bit-identical
    }
}

// readlane from lane-distributed 2-reg arrays; E is compile-time after full
// unroll -> constant lane index AND constant register index (rule #20 safe).
#define RLU(arr, E) ((unsigned)__builtin_amdgcn_readlane((int)arr[(E) >> 6], (E) & 63))
#define RLF(arr, E) __uint_as_float((unsigned)__builtin_amdgcn_readlane( \
                        (int)__float_as_uint(arr[(E) >> 6]), (E) & 63))

__global__ __launch_bounds__(BLOCK)
void EvolvedNet_80032420593868_kernel(const float* __restrict__ x,
                                      const unsigned* __restrict__ sodo,
                                      const float*    __restrict__ wk,
                                      float*          __restrict__ out) {
    // vals[node*BLOCK + tid]: wave-uniform node index -> 64 lanes on
    // consecutive banks (2 lanes/bank = free). Typed indexing only (R4),
    // no atomics (R6), no SMEM in loop (R7).
    __shared__ float vals[N_NODES * BLOCK];

    const int tid  = threadIdx.x;
    const int lane = tid & 63;
    const int b    = blockIdx.x * BLOCK + tid;

    // ---- preload all edge constants into lane-distributed VGPRs ----
    unsigned rsodo[2];
    float    rwk[2];
    rsodo[0] = sodo[lane];  rsodo[1] = sodo[lane + 64];
    rwk[0]   = wk[lane];    rwk[1]   = wk[lane + 64];

    // ---- init node state ----
#pragma unroll
    for (int n = 0; n < N_INPUTS; ++n)
        vals[n * BLOCK + tid] = x[n * BATCH + b];
#pragma unroll
    for (int n = N_INPUTS; n < N_NODES; ++n)
        vals[n * BLOCK + tid] = 0.0f;

    // No __syncthreads: each thread touches only its own column; the
    // per-wave DS pipe executes in order -> sequential edge semantics.

    // Prologue: read-ahead for edge 0 (sees the init state).
    unsigned p0 = RLU(rsodo, 0);
    int   iS = (int)(p0 & 0xFFFFu) + tid;
    int   iD = (int)(p0 >> 16) + tid;
    float ps = vals[iS];
    float pd = vals[iD];

    for (int sweep = 0; sweep < N_NODES; ++sweep) {
        // Full unroll: compile-time readlane indices, ~12-instr body (fits
        // I$), pipeline registers rename under SSA.
#pragma unroll
        for (int e = 0; e < N_EDGES; ++e) {
            // consume values read last iteration (post-write(e-1) => exact)
            const float wkv = RLF(rwk, e);
            const float a   = ps * wkv;
            const float u   = __builtin_amdgcn_exp2f(a);
            const float rc  = __builtin_amdgcn_rcpf(1.0f + u);
            const float t   = __builtin_fmaf(-2.0f, rc, 1.0f);

            vals[iD] = pd + t;                 // write(e), in-order DS

            // read-ahead for edge e+1 (cyclic across sweeps), AFTER the
            // write in program order -> sees write(e) if it aliases.
            const unsigned pn = RLU(rsodo, (e + 1) & (N_EDGES - 1));
            iS = (int)(pn & 0xFFFFu) + tid;
            iD = (int)(pn >> 16) + tid;
            ps = vals[iS];
            pd = vals[iD];
        }
    }

    // outputs: tanh(vals[28..31]); reads ordered after all writes.
#pragma unroll
    for (int o = 0; o < N_OUTPUTS; ++o) {
        const float v = vals[(N_NODES - N_OUTPUTS + o) * BLOCK + tid];
        const float u = __builtin_amdgcn_exp2f(v * TWO_LOG2E);
        out[o * BATCH + b] = __builtin_fmaf(-2.0f, __builtin_amdgcn_rcpf(1.0f + u), 1.0f);
    }
}

extern "C" void kernel_launch(void* const* d_in, const int* in_sizes, int n_in,
                              void* d_out, int out_size, void* d_ws, size_t ws_size,
                              hipStream_t stream) {
    const float* x   = (const float*)d_in[0];
    const float* w   = (const float*)d_in[1];
    const int*   src = (const int*)d_in[2];
    const int*   dst = (const int*)d_in[3];
    float*       out = (float*)d_out;

    // d_ws layout: sodo[128] (512B) | wk[128] (512B)
    unsigned* sodop = (unsigned*)d_ws;
    float*    wkp   = (float*)(sodop + N_EDGES);

    EvolvedNet_prep<<<1, 128, 0, stream>>>(w, src, dst, sodop, wkp);

    const int grid = BATCH / BLOCK;  // 2048 blocks, exact
    EvolvedNet_80032420593868_kernel<<<grid, BLOCK, 0, stream>>>(x, sodop, wkp, out);
}